// Round 12
// baseline (59.214 us; speedup 1.0000x reference)
//
#include <hip/hip_runtime.h>

// Problem constants (fixed by setup_inputs)
#define N_BATCH 32
#define C_IN    64
#define H_IN    32
#define W_IN    32
#define C_OUT   512
#define H_OUT   32
#define W_OUT   32

#define PH      34                 // padded plane height/width
#define PSTRIDE (PH * PH)          // 1156 floats per padded plane

typedef float f32x4 __attribute__((ext_vector_type(4)));

__device__ __forceinline__ void op_coeffs(int i, float& c0, float& c1, float& c2, float& c3) {
    constexpr float T[16][4] = {
        {0.f,0.f,0.f,0.f}, {0.f,0.f,0.f,1.f}, {0.f,1.f,0.f,-1.f}, {0.f,1.f,0.f,0.f},
        {0.f,0.f,1.f,-1.f}, {0.f,0.f,1.f,0.f}, {0.f,1.f,1.f,-2.f}, {0.f,1.f,1.f,-1.f},
        {1.f,-1.f,-1.f,1.f}, {1.f,-1.f,-1.f,2.f}, {1.f,0.f,-1.f,0.f}, {1.f,0.f,-1.f,1.f},
        {1.f,-1.f,0.f,0.f}, {1.f,-1.f,0.f,1.f}, {1.f,0.f,0.f,-1.f}, {1.f,0.f,0.f,0.f}
    };
    c0 = T[i][0]; c1 = T[i][1]; c2 = T[i][2]; c3 = T[i][3];
}

// ---------- prep: blocks 0..7 -> coef table; blocks 8..2055 -> padded x ----------
__global__ __launch_bounds__(256)
void prep_kernel(const float* __restrict__ x,
                 const float* __restrict__ weights,
                 f32x4* __restrict__ coef,
                 float* __restrict__ xpad) {
    const int blk = blockIdx.x;
    if (blk < 8) {
        const int idx = blk * 256 + threadIdx.x;       // (c*4+p), 0..2047
        const float* w = weights + idx * 16;
        float v[16];
        float m = -3.402823466e+38f;
        #pragma unroll
        for (int i = 0; i < 16; ++i) { v[i] = w[i]; m = fmaxf(m, v[i]); }
        float ssum = 0.f;
        #pragma unroll
        for (int i = 0; i < 16; ++i) { v[i] = __expf(v[i] - m); ssum += v[i]; }
        const float inv = 1.0f / ssum;
        float c0 = 0.f, c1 = 0.f, c2 = 0.f, c3 = 0.f;
        #pragma unroll
        for (int i = 0; i < 16; ++i) {
            float t0, t1, t2, t3;
            op_coeffs(i, t0, t1, t2, t3);
            c0 = fmaf(v[i], t0, c0);
            c1 = fmaf(v[i], t1, c1);
            c2 = fmaf(v[i], t2, c2);
            c3 = fmaf(v[i], t3, c3);
        }
        f32x4 out; out.x = c0 * inv; out.y = c1 * inv; out.z = c2 * inv; out.w = c3 * inv;
        coef[idx] = out;
    } else {
        const int p = blk - 8;                          // plane = n*64 + ch, 0..2047
        const float* __restrict__ src = x    + (size_t)p * (H_IN * W_IN);
        float*       __restrict__ dst = xpad + (size_t)p * PSTRIDE;
        for (int e = threadIdx.x; e < PSTRIDE; e += 256) {
            const int r  = e / PH;                      // 0..33 (magic-mul)
            const int cc = e - r * PH;                  // 0..33
            const unsigned ri = (unsigned)(r - 1), ci = (unsigned)(cc - 1);
            float v = (ri < W_IN && ci < W_IN) ? src[ri * W_IN + ci] : 0.0f;
            dst[e] = v;
        }
    }
}

// ---------- main: unconditional gathers from padded planes ----------
// Each of the 8 gather streams is a block-uniform base pointer (SGPR pair);
// the only per-lane state is poff, shared by all 8 gathers and bumped by a
// constant per k-step. Per gather: one global_load, zero VALU address math.
__global__ __launch_bounds__(256)
void conv_main_padded(const float* __restrict__ xpad,
                      const f32x4* __restrict__ coef,
                      const int*   __restrict__ sel,
                      float* __restrict__ y) {
    const int c = blockIdx.x;   // C_OUT
    const int n = blockIdx.y;   // N

    const int s0 = sel[c * 8 + 0], s1 = sel[c * 8 + 1];
    const int s2 = sel[c * 8 + 2], s3 = sel[c * 8 + 3];
    const int s4 = sel[c * 8 + 4], s5 = sel[c * 8 + 5];
    const int s6 = sel[c * 8 + 6], s7 = sel[c * 8 + 7];
    const f32x4 cf0 = coef[c * 4 + 0];
    const f32x4 cf1 = coef[c * 4 + 1];
    const f32x4 cf2 = coef[c * 4 + 2];
    const f32x4 cf3 = coef[c * 4 + 3];

    const float* __restrict__ pb = xpad + (size_t)n * (C_IN * PSTRIDE);
    #define PLANE(s) (pb + ((s) >> 16) * PSTRIDE + (((s) >> 8) & 0xff) * PH + ((s) & 0xff))
    const float* __restrict__ p0 = PLANE(s0);
    const float* __restrict__ p1 = PLANE(s1);
    const float* __restrict__ p2 = PLANE(s2);
    const float* __restrict__ p3 = PLANE(s3);
    const float* __restrict__ p4 = PLANE(s4);
    const float* __restrict__ p5 = PLANE(s5);
    const float* __restrict__ p6 = PLANE(s6);
    const float* __restrict__ p7 = PLANE(s7);
    #undef PLANE

    f32x4* __restrict__ yv = reinterpret_cast<f32x4*>(y) +
                             (size_t)(n * C_OUT + c) * (H_OUT * W_OUT);

    int pos  = threadIdx.x;                       // output position 0..1023
    int poff = (pos >> 5) * PH + (pos & 31);      // padded-plane offset

    #pragma unroll
    for (int k = 0; k < 4; ++k) {
        const float a0 = p0[poff], b0 = p1[poff];
        const float a1 = p2[poff], b1 = p3[poff];
        const float a2 = p4[poff], b2 = p5[poff];
        const float a3 = p6[poff], b3 = p7[poff];

        f32x4 out;
        out.x = fmaf(cf0.w * a0, b0, fmaf(cf0.y, a0, fmaf(cf0.z, b0, cf0.x)));
        out.y = fmaf(cf1.w * a1, b1, fmaf(cf1.y, a1, fmaf(cf1.z, b1, cf1.x)));
        out.z = fmaf(cf2.w * a2, b2, fmaf(cf2.y, a2, fmaf(cf2.z, b2, cf2.x)));
        out.w = fmaf(cf3.w * a3, b3, fmaf(cf3.y, a3, fmaf(cf3.z, b3, cf3.x)));

        __builtin_nontemporal_store(out, &yv[pos]);

        pos  += 256;
        poff += 8 * PH;   // 8 rows per 256 positions
    }
}

// ---------- fused fallback (if d_ws too small) — proven R8 structure ----------
__device__ __forceinline__ float gather_x(const float* __restrict__ x,
                                          int nbase, int s, int oh, int ow) {
    int ch = (s >> 16) & 0xffff;
    int ry = (s >> 8) & 0xff;
    int rx = s & 0xff;
    int r = oh + ry - 1;
    int c = ow + rx - 1;
    bool ok = ((unsigned)r < (unsigned)H_IN) && ((unsigned)c < (unsigned)W_IN);
    return ok ? x[nbase + ch * (H_IN * W_IN) + r * W_IN + c] : 0.0f;
}

__global__ __launch_bounds__(256)
void conv_fused_kernel(const float* __restrict__ x,
                       const float* __restrict__ weights,
                       const int*   __restrict__ sel,
                       float* __restrict__ y) {
    const int c = blockIdx.x;
    const int n = blockIdx.y;

    __shared__ float4 s_coef[4];
    __shared__ int    s_sel[8];

    if (threadIdx.x < 8) s_sel[threadIdx.x] = sel[c * 8 + threadIdx.x];
    if (threadIdx.x < 4) {
        const int p = threadIdx.x;
        const float* w = weights + (c * 4 + p) * 16;
        float v[16];
        float m = -3.402823466e+38f;
        #pragma unroll
        for (int i = 0; i < 16; ++i) { v[i] = w[i]; m = fmaxf(m, v[i]); }
        float ssum = 0.f;
        #pragma unroll
        for (int i = 0; i < 16; ++i) { v[i] = __expf(v[i] - m); ssum += v[i]; }
        const float inv = 1.0f / ssum;
        float c0 = 0.f, c1 = 0.f, c2 = 0.f, c3 = 0.f;
        #pragma unroll
        for (int i = 0; i < 16; ++i) {
            float t0, t1, t2, t3;
            op_coeffs(i, t0, t1, t2, t3);
            c0 = fmaf(v[i], t0, c0);
            c1 = fmaf(v[i], t1, c1);
            c2 = fmaf(v[i], t2, c2);
            c3 = fmaf(v[i], t3, c3);
        }
        s_coef[p] = make_float4(c0 * inv, c1 * inv, c2 * inv, c3 * inv);
    }
    __syncthreads();

    const int nbase = n * (C_IN * H_IN * W_IN);
    f32x4* __restrict__ yv = reinterpret_cast<f32x4*>(y) +
                             (size_t)(n * C_OUT + c) * (H_OUT * W_OUT);

    const float4 cf0 = s_coef[0], cf1 = s_coef[1], cf2 = s_coef[2], cf3 = s_coef[3];
    const int sl0 = s_sel[0], sl1 = s_sel[1], sl2 = s_sel[2], sl3 = s_sel[3];
    const int sl4 = s_sel[4], sl5 = s_sel[5], sl6 = s_sel[6], sl7 = s_sel[7];

    #pragma unroll
    for (int k = 0; k < 4; ++k) {
        const int pos = threadIdx.x + k * 256;
        const int oh = pos >> 5;
        const int ow = pos & 31;
        float a, b;
        f32x4 out;
        a = gather_x(x, nbase, sl0, oh, ow);
        b = gather_x(x, nbase, sl1, oh, ow);
        out.x = fmaf(cf0.w * a, b, fmaf(cf0.y, a, fmaf(cf0.z, b, cf0.x)));
        a = gather_x(x, nbase, sl2, oh, ow);
        b = gather_x(x, nbase, sl3, oh, ow);
        out.y = fmaf(cf1.w * a, b, fmaf(cf1.y, a, fmaf(cf1.z, b, cf1.x)));
        a = gather_x(x, nbase, sl4, oh, ow);
        b = gather_x(x, nbase, sl5, oh, ow);
        out.z = fmaf(cf2.w * a, b, fmaf(cf2.y, a, fmaf(cf2.z, b, cf2.x)));
        a = gather_x(x, nbase, sl6, oh, ow);
        b = gather_x(x, nbase, sl7, oh, ow);
        out.w = fmaf(cf3.w * a, b, fmaf(cf3.y, a, fmaf(cf3.z, b, cf3.x)));
        __builtin_nontemporal_store(out, &yv[pos]);
    }
}

extern "C" void kernel_launch(void* const* d_in, const int* in_sizes, int n_in,
                              void* d_out, int out_size, void* d_ws, size_t ws_size,
                              hipStream_t stream) {
    const float* x       = (const float*)d_in[0];
    const float* weights = (const float*)d_in[1];
    const int*   sel     = (const int*)d_in[2];
    float* y             = (float*)d_out;

    const size_t coef_bytes = (size_t)C_OUT * 4 * sizeof(f32x4);            // 32 KB
    const size_t pad_bytes  = (size_t)N_BATCH * C_IN * PSTRIDE * sizeof(float); // ~9.5 MB
    dim3 grid(C_OUT, N_BATCH);

    if (ws_size >= coef_bytes + pad_bytes) {
        f32x4* coef = (f32x4*)d_ws;
        float* xpad = (float*)((char*)d_ws + coef_bytes);
        prep_kernel<<<dim3(8 + N_BATCH * C_IN), 256, 0, stream>>>(x, weights, coef, xpad);
        conv_main_padded<<<grid, 256, 0, stream>>>(xpad, coef, sel, y);
    } else {
        conv_fused_kernel<<<grid, 256, 0, stream>>>(x, weights, sel, y);
    }
}